// Round 1
// baseline (2164.184 us; speedup 1.0000x reference)
//
#include <hip/hip_runtime.h>
#include <hip/hip_bf16.h>
#include <math.h>

#define B_SZ 16
#define T_SZ 128
#define N_P 12
#define D_SZ 1024
#define D2_SZ 2048
#define BT (B_SZ * T_SZ)

// ---------------------------------------------------------------------------
// Kernel A: build n = [g ; max] per token.
// One block per token (b*T+t). features token stride = N_P*D_SZ.
// ---------------------------------------------------------------------------
__global__ __launch_bounds__(256) void build_n_kernel(
    const float* __restrict__ feat, const float* __restrict__ Wq,
    float* __restrict__ Nmat) {
  const int t = blockIdx.x;      // 0..BT-1
  const int tid = threadIdx.x;   // 0..255
  const float* fbase = feat + (size_t)t * N_P * D_SZ;

  float part[N_P];
#pragma unroll
  for (int n = 0; n < N_P; ++n) part[n] = 0.f;
  float fv[4][N_P];

#pragma unroll
  for (int it = 0; it < 4; ++it) {
    const int d = tid + it * 256;
    float q = 0.f;
#pragma unroll
    for (int m = 0; m < N_P; ++m) q += Wq[m * D_SZ + d];
#pragma unroll
    for (int n = 0; n < N_P; ++n) {
      const float f = fbase[n * D_SZ + d];
      fv[it][n] = f;
      part[n] += f * q;
    }
  }

  // reduce part[n] across the block: wave shuffle then LDS across 4 waves
  __shared__ float wred[N_P * 4];
  const int lane = tid & 63;
  const int wave = tid >> 6;
#pragma unroll
  for (int n = 0; n < N_P; ++n) {
    float v = part[n];
#pragma unroll
    for (int off = 32; off; off >>= 1) v += __shfl_down(v, off);
    if (lane == 0) wred[n * 4 + wave] = v;
  }
  __syncthreads();

  float w[N_P];
#pragma unroll
  for (int n = 0; n < N_P; ++n)
    w[n] = wred[n * 4 + 0] + wred[n * 4 + 1] + wred[n * 4 + 2] + wred[n * 4 + 3];

#pragma unroll
  for (int it = 0; it < 4; ++it) {
    const int d = tid + it * 256;
    float g = 0.f;
    float fm = -INFINITY;
#pragma unroll
    for (int n = 0; n < N_P; ++n) {
      g += w[n] * fv[it][n];
      fm = fmaxf(fm, fv[it][n]);
    }
    Nmat[(size_t)t * D2_SZ + d] = g;
    Nmat[(size_t)t * D2_SZ + D_SZ + d] = fm;
  }
}

// ---------------------------------------------------------------------------
// Kernel B: C[M,E] = X[M,K] * W[E,K]^T   (both row-major, K inner)
// 64x64 block tile, 4x4 microtile, K-tile 16. M=2048 fixed by grid.
// ---------------------------------------------------------------------------
#define GM 64
#define GE 64
#define GK 16

__global__ __launch_bounds__(256) void gemm_abt(
    const float* __restrict__ X, const float* __restrict__ W,
    float* __restrict__ C, int K, int E) {
  __shared__ float Xs[GK][GM + 1];
  __shared__ float Ws[GK][GE + 1];
  const int tid = threadIdx.x;
  const int tx = tid & 15;   // e micro index
  const int ty = tid >> 4;   // m micro index
  const int m0 = blockIdx.x * GM;
  const int e0 = blockIdx.y * GE;

  const int lc = tid & 15;   // k col for loading
  const int lr = tid >> 4;   // row base 0..15

  float acc[4][4];
#pragma unroll
  for (int i = 0; i < 4; ++i)
#pragma unroll
    for (int j = 0; j < 4; ++j) acc[i][j] = 0.f;

  for (int k0 = 0; k0 < K; k0 += GK) {
#pragma unroll
    for (int r = 0; r < 4; ++r) {
      const int row = lr + r * 16;
      Xs[lc][row] = X[(size_t)(m0 + row) * K + k0 + lc];
      Ws[lc][row] = W[(size_t)(e0 + row) * K + k0 + lc];
    }
    __syncthreads();
#pragma unroll
    for (int k = 0; k < GK; ++k) {
      float xv[4], wv[4];
#pragma unroll
      for (int i = 0; i < 4; ++i) xv[i] = Xs[k][ty * 4 + i];
#pragma unroll
      for (int j = 0; j < 4; ++j) wv[j] = Ws[k][tx * 4 + j];
#pragma unroll
      for (int i = 0; i < 4; ++i)
#pragma unroll
        for (int j = 0; j < 4; ++j) acc[i][j] += xv[i] * wv[j];
    }
    __syncthreads();
  }

#pragma unroll
  for (int i = 0; i < 4; ++i) {
    const int m = m0 + ty * 4 + i;
#pragma unroll
    for (int j = 0; j < 4; ++j) {
      C[(size_t)m * E + e0 + tx * 4 + j] = acc[i][j];
    }
  }
}

// ---------------------------------------------------------------------------
// Kernel C: per (b,i): s_b[j] = scale * <tb_i, pb_j>, s_a[j] = scale * <ta_i, pa_j>
//   out[i] = n[i] + sum_{j<i} s_b[j]*gb[j] + sum_{j>i} s_a[j]*ga[j]
// ---------------------------------------------------------------------------
__global__ __launch_bounds__(256) void attn_kernel(
    const float* __restrict__ Nmat,
    const float* __restrict__ tbm, const float* __restrict__ pbm,
    const float* __restrict__ gbm,
    const float* __restrict__ tam, const float* __restrict__ pam,
    const float* __restrict__ gam,
    float* __restrict__ out) {
  const int i = blockIdx.x;   // 0..127 query index
  const int b = blockIdx.y;   // 0..15 batch
  const int tid = threadIdx.x;
  const int lane = tid & 63;
  const int wave = tid >> 6;
  const int tbase = b * T_SZ;
  const float scale = 0.022097086912079608f;  // 1/sqrt(2048)

  __shared__ float4 stb4[D_SZ / 4];
  __shared__ float4 sta4[D_SZ / 4];
  __shared__ float sb[T_SZ];
  __shared__ float sa[T_SZ];

  {
    const float4* tb4 = (const float4*)(tbm + (size_t)(tbase + i) * D_SZ);
    const float4* ta4 = (const float4*)(tam + (size_t)(tbase + i) * D_SZ);
    stb4[tid] = tb4[tid];
    sta4[tid] = ta4[tid];
  }
  __syncthreads();

  // scores: wave w handles j = w*32 + jj
  for (int jj = 0; jj < 32; ++jj) {
    const int j = wave * 32 + jj;
    const float4* pbr = (const float4*)(pbm + (size_t)(tbase + j) * D_SZ);
    const float4* par = (const float4*)(pam + (size_t)(tbase + j) * D_SZ);
    float accB = 0.f, accA = 0.f;
#pragma unroll
    for (int c = 0; c < 4; ++c) {
      const int idx = lane + c * 64;
      const float4 x = stb4[idx];
      const float4 y = pbr[idx];
      accB += x.x * y.x + x.y * y.y + x.z * y.z + x.w * y.w;
      const float4 u = sta4[idx];
      const float4 v = par[idx];
      accA += u.x * v.x + u.y * v.y + u.z * v.z + u.w * v.w;
    }
#pragma unroll
    for (int off = 32; off; off >>= 1) {
      accB += __shfl_down(accB, off);
      accA += __shfl_down(accA, off);
    }
    if (lane == 0) {
      sb[j] = accB * scale;
      sa[j] = accA * scale;
    }
  }
  __syncthreads();

  // epilogue: out row i (2048 floats = 512 float4), strict triangular sums
  const float4* nrow = (const float4*)(Nmat + (size_t)(tbase + i) * D2_SZ);
  float4* orow = (float4*)(out + (size_t)(tbase + i) * D2_SZ);
#pragma unroll
  for (int it = 0; it < 2; ++it) {
    const int ff = tid + it * 256;
    float4 acc = nrow[ff];
    for (int j = 0; j < i; ++j) {
      const float s = sb[j];
      const float4 g = ((const float4*)(gbm + (size_t)(tbase + j) * D2_SZ))[ff];
      acc.x += s * g.x; acc.y += s * g.y; acc.z += s * g.z; acc.w += s * g.w;
    }
    for (int j = i + 1; j < T_SZ; ++j) {
      const float s = sa[j];
      const float4 g = ((const float4*)(gam + (size_t)(tbase + j) * D2_SZ))[ff];
      acc.x += s * g.x; acc.y += s * g.y; acc.z += s * g.z; acc.w += s * g.w;
    }
    orow[ff] = acc;
  }
}

// ---------------------------------------------------------------------------
extern "C" void kernel_launch(void* const* d_in, const int* in_sizes, int n_in,
                              void* d_out, int out_size, void* d_ws, size_t ws_size,
                              hipStream_t stream) {
  const float* feat = (const float*)d_in[0];
  const float* Wq  = (const float*)d_in[1];
  const float* Wtb = (const float*)d_in[2];
  const float* Wpb = (const float*)d_in[3];
  const float* Wgb = (const float*)d_in[4];
  const float* Wta = (const float*)d_in[5];
  const float* Wpa = (const float*)d_in[6];
  const float* Wga = (const float*)d_in[7];
  float* out = (float*)d_out;

  float* ws = (float*)d_ws;
  float* Nmat = ws;                        // BT x 2048
  float* tb = Nmat + (size_t)BT * D2_SZ;   // BT x 1024
  float* pb = tb + (size_t)BT * D_SZ;
  float* ta = pb + (size_t)BT * D_SZ;
  float* pa = ta + (size_t)BT * D_SZ;
  float* gb = pa + (size_t)BT * D_SZ;      // BT x 2048
  float* ga = gb + (size_t)BT * D2_SZ;

  build_n_kernel<<<BT, 256, 0, stream>>>(feat, Wq, Nmat);

  dim3 blk(256);
  dim3 g1(BT / GM, D_SZ / GE);    // E = 1024
  dim3 g2(BT / GM, D2_SZ / GE);   // E = 2048
  gemm_abt<<<g1, blk, 0, stream>>>(Nmat, Wtb, tb, D2_SZ, D_SZ);
  gemm_abt<<<g1, blk, 0, stream>>>(Nmat, Wpb, pb, D2_SZ, D_SZ);
  gemm_abt<<<g1, blk, 0, stream>>>(Nmat, Wta, ta, D2_SZ, D_SZ);
  gemm_abt<<<g1, blk, 0, stream>>>(Nmat, Wpa, pa, D2_SZ, D_SZ);
  gemm_abt<<<g2, blk, 0, stream>>>(Nmat, Wgb, gb, D2_SZ, D2_SZ);
  gemm_abt<<<g2, blk, 0, stream>>>(Nmat, Wga, ga, D2_SZ, D2_SZ);

  attn_kernel<<<dim3(T_SZ, B_SZ), blk, 0, stream>>>(Nmat, tb, pb, gb, ta, pa, ga, out);
}

// Round 2
// 388.843 us; speedup vs baseline: 5.5657x; 5.5657x over previous
//
#include <hip/hip_runtime.h>
#include <hip/hip_bf16.h>
#include <math.h>

#define B_SZ 16
#define T_SZ 128
#define N_P 12
#define D_SZ 1024
#define D2_SZ 2048
#define BT 2048          // B*T tokens
#define KDIM 2048        // inner dim of projections (2D)
#define EALL 8192        // 4*1024 (tb,pb,ta,pa) + 2*2048 (gb,ga)

typedef __attribute__((ext_vector_type(8))) short short8;    // 8 bf16 = 4 VGPRs
typedef __attribute__((ext_vector_type(4))) float floatx4;   // MFMA C/D

__device__ inline void gload_lds16(const void* g, void* l) {
  __builtin_amdgcn_global_load_lds(
      (const __attribute__((address_space(1))) void*)g,
      (__attribute__((address_space(3))) void*)l, 16, 0, 0);
}

__device__ inline unsigned short f2bf(float x) {
  union { __hip_bfloat16 h; unsigned short u; } cv;
  cv.h = __float2bfloat16(x);
  return cv.u;
}
__device__ inline float bf2f(unsigned short u) {
  return __uint_as_float(((unsigned)u) << 16);
}

// ---------------------------------------------------------------------------
// Kernel A: build n = [g ; max] per token, output bf16. One block per token.
// ---------------------------------------------------------------------------
__global__ __launch_bounds__(256) void build_n_kernel(
    const float* __restrict__ feat, const float* __restrict__ Wq,
    unsigned short* __restrict__ Nbf) {
  const int t = blockIdx.x;
  const int tid = threadIdx.x;
  const float* fbase = feat + (size_t)t * N_P * D_SZ;

  float part[N_P];
#pragma unroll
  for (int n = 0; n < N_P; ++n) part[n] = 0.f;
  float fv[4][N_P];

#pragma unroll
  for (int it = 0; it < 4; ++it) {
    const int d = tid + it * 256;
    float q = 0.f;
#pragma unroll
    for (int m = 0; m < N_P; ++m) q += Wq[m * D_SZ + d];
#pragma unroll
    for (int n = 0; n < N_P; ++n) {
      const float f = fbase[n * D_SZ + d];
      fv[it][n] = f;
      part[n] += f * q;
    }
  }

  __shared__ float wred[N_P * 4];
  const int lane = tid & 63;
  const int wave = tid >> 6;
#pragma unroll
  for (int n = 0; n < N_P; ++n) {
    float v = part[n];
#pragma unroll
    for (int off = 32; off; off >>= 1) v += __shfl_down(v, off);
    if (lane == 0) wred[n * 4 + wave] = v;
  }
  __syncthreads();

  float w[N_P];
#pragma unroll
  for (int n = 0; n < N_P; ++n)
    w[n] = wred[n * 4 + 0] + wred[n * 4 + 1] + wred[n * 4 + 2] + wred[n * 4 + 3];

#pragma unroll
  for (int it = 0; it < 4; ++it) {
    const int d = tid + it * 256;
    float g = 0.f;
    float fm = -INFINITY;
#pragma unroll
    for (int n = 0; n < N_P; ++n) {
      g += w[n] * fv[it][n];
      fm = fmaxf(fm, fv[it][n]);
    }
    Nbf[(size_t)t * D2_SZ + d] = f2bf(g);
    Nbf[(size_t)t * D2_SZ + D_SZ + d] = f2bf(fm);
  }
}

// ---------------------------------------------------------------------------
// fp32 -> bf16 convert (vectorized x4)
// ---------------------------------------------------------------------------
__global__ __launch_bounds__(256) void cvt_bf16(
    const float* __restrict__ src, unsigned short* __restrict__ dst, int n4) {
  const int i = blockIdx.x * 256 + threadIdx.x;
  if (i < n4) {
    const float4 v = ((const float4*)src)[i];
    ushort4 o;
    o.x = f2bf(v.x); o.y = f2bf(v.y); o.z = f2bf(v.z); o.w = f2bf(v.w);
    ((ushort4*)dst)[i] = o;
  }
}

// ---------------------------------------------------------------------------
// Kernel B: fused projection GEMM, bf16 MFMA.
// C[BT, EALL] = X[BT, KDIM] * Wb[EALL, KDIM]^T, C stored bf16.
// 128x128 tile, 4 waves (2x2), 16x16x32 bf16 MFMA, BK=32,
// global_load_lds width-16 staging (contiguous [row][32] LDS layout).
// ---------------------------------------------------------------------------
__global__ __launch_bounds__(256) void gemm_fused(
    const unsigned short* __restrict__ X,
    const unsigned short* __restrict__ Wb,
    unsigned short* __restrict__ Call) {
  __shared__ __align__(16) unsigned short As[128 * 32];
  __shared__ __align__(16) unsigned short Bs[128 * 32];
  const int tid = threadIdx.x;
  const int lane = tid & 63;
  const int w = tid >> 6;
  const int m0 = blockIdx.x * 128;
  const int e0 = blockIdx.y * 128;
  const int wm = (w >> 1) * 64;
  const int wn = (w & 1) * 64;
  const int quad = lane >> 4;
  const int l15 = lane & 15;

  floatx4 acc[4][4];
#pragma unroll
  for (int mt = 0; mt < 4; ++mt)
#pragma unroll
    for (int nt = 0; nt < 4; ++nt) {
      floatx4 z = {0.f, 0.f, 0.f, 0.f};
      acc[mt][nt] = z;
    }

  // staging chunk assignment: 512 16B-chunks per 8KB tile, 2 per thread
  const unsigned short* gA[2];
  const unsigned short* gB[2];
  unsigned short* lA[2];
  unsigned short* lB[2];
#pragma unroll
  for (int c = 0; c < 2; ++c) {
    const int chunk = w * 64 + lane + c * 256;
    const int row = chunk >> 2;
    const int cc = chunk & 3;
    gA[c] = X + (size_t)(m0 + row) * KDIM + cc * 8;
    gB[c] = Wb + (size_t)(e0 + row) * KDIM + cc * 8;
    lA[c] = &As[(size_t)(w * 64 + c * 256) * 8];  // wave-uniform base
    lB[c] = &Bs[(size_t)(w * 64 + c * 256) * 8];
  }

  for (int k0 = 0; k0 < KDIM; k0 += 32) {
#pragma unroll
    for (int c = 0; c < 2; ++c) {
      gload_lds16(gA[c] + k0, lA[c]);
      gload_lds16(gB[c] + k0, lB[c]);
    }
    __syncthreads();
    short8 a[4], b[4];
#pragma unroll
    for (int mt = 0; mt < 4; ++mt)
      a[mt] = *(const short8*)&As[(wm + mt * 16 + l15) * 32 + quad * 8];
#pragma unroll
    for (int nt = 0; nt < 4; ++nt)
      b[nt] = *(const short8*)&Bs[(wn + nt * 16 + l15) * 32 + quad * 8];
#pragma unroll
    for (int mt = 0; mt < 4; ++mt)
#pragma unroll
      for (int nt = 0; nt < 4; ++nt)
        acc[mt][nt] = __builtin_amdgcn_mfma_f32_16x16x32_bf16(
            a[mt], b[nt], acc[mt][nt], 0, 0, 0);
    __syncthreads();
  }

#pragma unroll
  for (int mt = 0; mt < 4; ++mt)
#pragma unroll
    for (int nt = 0; nt < 4; ++nt) {
      const int col = e0 + wn + nt * 16 + l15;
#pragma unroll
      for (int r = 0; r < 4; ++r) {
        const int rowg = m0 + wm + mt * 16 + quad * 4 + r;
        Call[(size_t)rowg * EALL + col] = f2bf(acc[mt][nt][r]);
      }
    }
}

// ---------------------------------------------------------------------------
// Kernel C: masked scores via MFMA.
// S[br][b][i][j] = mask * scale * <A_i, B_j>, A/B = (tb,pb) or (ta,pa), K=1024.
// One block per (batch, branch): full 128x128 output.
// ---------------------------------------------------------------------------
__global__ __launch_bounds__(256) void score_kernel(
    const unsigned short* __restrict__ Call, float* __restrict__ Smat) {
  const int b = blockIdx.x;
  const int br = blockIdx.y;
  const int aoff = br ? 2048 : 0;   // ta : tb
  const int boff = aoff + 1024;     // pa : pb
  const float scale = 0.022097086912079608f;  // 1/sqrt(2*1024)

  __shared__ __align__(16) unsigned short As[128 * 32];
  __shared__ __align__(16) unsigned short Bs[128 * 32];
  const int tid = threadIdx.x;
  const int lane = tid & 63;
  const int w = tid >> 6;
  const int wm = (w >> 1) * 64;
  const int wn = (w & 1) * 64;
  const int quad = lane >> 4;
  const int l15 = lane & 15;
  const int t0 = b * T_SZ;

  floatx4 acc[4][4];
#pragma unroll
  for (int mt = 0; mt < 4; ++mt)
#pragma unroll
    for (int nt = 0; nt < 4; ++nt) {
      floatx4 z = {0.f, 0.f, 0.f, 0.f};
      acc[mt][nt] = z;
    }

  const unsigned short* gA[2];
  const unsigned short* gB[2];
  unsigned short* lA[2];
  unsigned short* lB[2];
#pragma unroll
  for (int c = 0; c < 2; ++c) {
    const int chunk = w * 64 + lane + c * 256;
    const int row = chunk >> 2;
    const int cc = chunk & 3;
    gA[c] = Call + (size_t)(t0 + row) * EALL + aoff + cc * 8;
    gB[c] = Call + (size_t)(t0 + row) * EALL + boff + cc * 8;
    lA[c] = &As[(size_t)(w * 64 + c * 256) * 8];
    lB[c] = &Bs[(size_t)(w * 64 + c * 256) * 8];
  }

  for (int k0 = 0; k0 < D_SZ; k0 += 32) {
#pragma unroll
    for (int c = 0; c < 2; ++c) {
      gload_lds16(gA[c] + k0, lA[c]);
      gload_lds16(gB[c] + k0, lB[c]);
    }
    __syncthreads();
    short8 a[4], bb[4];
#pragma unroll
    for (int mt = 0; mt < 4; ++mt)
      a[mt] = *(const short8*)&As[(wm + mt * 16 + l15) * 32 + quad * 8];
#pragma unroll
    for (int nt = 0; nt < 4; ++nt)
      bb[nt] = *(const short8*)&Bs[(wn + nt * 16 + l15) * 32 + quad * 8];
#pragma unroll
    for (int mt = 0; mt < 4; ++mt)
#pragma unroll
      for (int nt = 0; nt < 4; ++nt)
        acc[mt][nt] = __builtin_amdgcn_mfma_f32_16x16x32_bf16(
            a[mt], bb[nt], acc[mt][nt], 0, 0, 0);
    __syncthreads();
  }

  float* Sb = Smat + (((size_t)br * B_SZ + b) * T_SZ) * T_SZ;
#pragma unroll
  for (int mt = 0; mt < 4; ++mt)
#pragma unroll
    for (int nt = 0; nt < 4; ++nt) {
      const int j = wn + nt * 16 + l15;
#pragma unroll
      for (int r = 0; r < 4; ++r) {
        const int i = wm + mt * 16 + quad * 4 + r;
        const bool keep = br ? (j > i) : (j < i);
        Sb[(size_t)i * T_SZ + j] = keep ? acc[mt][nt][r] * scale : 0.f;
      }
    }
}

// ---------------------------------------------------------------------------
// Kernel D: out[b,i,:] = n[b,i,:] + sum_j Sb[i][j]*gb[j,:] + sum_j Sa[i][j]*ga[j,:]
// One block per (i, b); thread owns 8 consecutive f columns.
// ---------------------------------------------------------------------------
__global__ __launch_bounds__(256) void pv_kernel(
    const unsigned short* __restrict__ Nbf,
    const unsigned short* __restrict__ Call,
    const float* __restrict__ Smat,
    float* __restrict__ out) {
  const int i = blockIdx.x;
  const int b = blockIdx.y;
  const int tid = threadIdx.x;

  __shared__ float sb[T_SZ];
  __shared__ float sa[T_SZ];
  if (tid < 128) {
    sb[tid] = Smat[(((size_t)0 * B_SZ + b) * T_SZ + i) * T_SZ + tid];
  } else {
    sa[tid - 128] = Smat[(((size_t)1 * B_SZ + b) * T_SZ + i) * T_SZ + (tid - 128)];
  }
  __syncthreads();

  const int f0 = tid * 8;
  float acc[8];
  {
    const short8 nv = *(const short8*)(Nbf + (size_t)(b * T_SZ + i) * D2_SZ + f0);
#pragma unroll
    for (int q = 0; q < 8; ++q) acc[q] = bf2f((unsigned short)nv[q]);
  }

  const unsigned short* gbase = Call + 4096 + f0;         // gb col region
  const unsigned short* abase = Call + 4096 + 2048 + f0;  // ga col region
  for (int j = 0; j < i; ++j) {
    const float s = sb[j];
    const short8 v = *(const short8*)(gbase + (size_t)(b * T_SZ + j) * EALL);
#pragma unroll
    for (int q = 0; q < 8; ++q) acc[q] += s * bf2f((unsigned short)v[q]);
  }
  for (int j = i + 1; j < T_SZ; ++j) {
    const float s = sa[j];
    const short8 v = *(const short8*)(abase + (size_t)(b * T_SZ + j) * EALL);
#pragma unroll
    for (int q = 0; q < 8; ++q) acc[q] += s * bf2f((unsigned short)v[q]);
  }

  float* orow = out + (size_t)(b * T_SZ + i) * D2_SZ + f0;
#pragma unroll
  for (int q = 0; q < 8; ++q) orow[q] = acc[q];
}

// ---------------------------------------------------------------------------
extern "C" void kernel_launch(void* const* d_in, const int* in_sizes, int n_in,
                              void* d_out, int out_size, void* d_ws, size_t ws_size,
                              hipStream_t stream) {
  const float* feat = (const float*)d_in[0];
  const float* Wq  = (const float*)d_in[1];
  const float* Wtb = (const float*)d_in[2];
  const float* Wpb = (const float*)d_in[3];
  const float* Wgb = (const float*)d_in[4];  // NOTE: dict order — gb before ta
  const float* Wta = (const float*)d_in[5];
  const float* Wpa = (const float*)d_in[6];
  const float* Wga = (const float*)d_in[7];
  float* out = (float*)d_out;

  unsigned short* ws = (unsigned short*)d_ws;
  unsigned short* Nbf  = ws;                               // [BT][2048] bf16
  unsigned short* Wb   = Nbf + (size_t)BT * D2_SZ;         // [EALL][2048] bf16
  unsigned short* Call = Wb + (size_t)EALL * KDIM;         // [BT][EALL] bf16
  float* Smat = (float*)(Call + (size_t)BT * EALL);        // [2][16][128][128] f32

  build_n_kernel<<<BT, 256, 0, stream>>>(feat, Wq, Nbf);

  // weight conversion into Wb rows: [tb | pb | ta | pa | gb | ga]
  {
    const int n4s = (1024 * 2048) / 4;   // small weights
    const int n4g = (2048 * 2048) / 4;   // g weights
    cvt_bf16<<<(n4s + 255) / 256, 256, 0, stream>>>(Wtb, Wb + (size_t)0 * KDIM, n4s);
    cvt_bf16<<<(n4s + 255) / 256, 256, 0, stream>>>(Wpb, Wb + (size_t)1024 * KDIM, n4s);
    cvt_bf16<<<(n4s + 255) / 256, 256, 0, stream>>>(Wta, Wb + (size_t)2048 * KDIM, n4s);
    cvt_bf16<<<(n4s + 255) / 256, 256, 0, stream>>>(Wpa, Wb + (size_t)3072 * KDIM, n4s);
    cvt_bf16<<<(n4g + 255) / 256, 256, 0, stream>>>(Wgb, Wb + (size_t)4096 * KDIM, n4g);
    cvt_bf16<<<(n4g + 255) / 256, 256, 0, stream>>>(Wga, Wb + (size_t)6144 * KDIM, n4g);
  }

  gemm_fused<<<dim3(BT / 128, EALL / 128), 256, 0, stream>>>(Nbf, Wb, Call);
  score_kernel<<<dim3(B_SZ, 2), 256, 0, stream>>>(Call, Smat);
  pv_kernel<<<dim3(T_SZ, B_SZ), 256, 0, stream>>>(Nbf, Call, Smat, out);
}

// Round 4
// 342.687 us; speedup vs baseline: 6.3153x; 1.1347x over previous
//
#include <hip/hip_runtime.h>
#include <hip/hip_bf16.h>
#include <math.h>

#define B_SZ 16
#define T_SZ 128
#define N_P 12
#define D_SZ 1024
#define D2_SZ 2048
#define BT 2048          // B*T tokens
#define KDIM 2048        // inner dim of projections (2D)
#define EALL 8192        // 4*1024 (tb,pb,ta,pa) + 2*2048 (gb,ga)
#define EPROJ 4096       // tb|pb|ta|pa row width

typedef __attribute__((ext_vector_type(8))) short short8;    // 8 bf16 = 4 VGPRs
typedef __attribute__((ext_vector_type(4))) float floatx4;   // MFMA C/D

__device__ inline void gload_lds16(const void* g, void* l) {
  __builtin_amdgcn_global_load_lds(
      (const __attribute__((address_space(1))) void*)g,
      (__attribute__((address_space(3))) void*)l, 16, 0, 0);
}

__device__ inline unsigned short f2bf(float x) {
  union { __hip_bfloat16 h; unsigned short u; } cv;
  cv.h = __float2bfloat16(x);
  return cv.u;
}
__device__ inline float bf2f(unsigned short u) {
  return __uint_as_float(((unsigned)u) << 16);
}

// ---------------------------------------------------------------------------
// Kernel A: build n = [g ; max] per token, bf16 out. One block per token.
// Thread owns 4 consecutive d (float4 loads, ushort4 stores).
// ---------------------------------------------------------------------------
__global__ __launch_bounds__(256) void build_n_kernel(
    const float* __restrict__ feat, const float* __restrict__ Wq,
    unsigned short* __restrict__ Nbf) {
  const int t = blockIdx.x;
  const int tid = threadIdx.x;
  const float4* fb4 = (const float4*)(feat + (size_t)t * N_P * D_SZ);
  const float4* wq4 = (const float4*)Wq;

  float4 q = {0.f, 0.f, 0.f, 0.f};
#pragma unroll
  for (int m = 0; m < N_P; ++m) {
    const float4 v = wq4[m * 256 + tid];
    q.x += v.x; q.y += v.y; q.z += v.z; q.w += v.w;
  }

  float4 fv[N_P];
  float part[N_P];
#pragma unroll
  for (int n = 0; n < N_P; ++n) {
    const float4 f = fb4[n * 256 + tid];
    fv[n] = f;
    part[n] = f.x * q.x + f.y * q.y + f.z * q.z + f.w * q.w;
  }

  __shared__ float wred[N_P * 4];
  const int lane = tid & 63;
  const int wave = tid >> 6;
#pragma unroll
  for (int n = 0; n < N_P; ++n) {
    float v = part[n];
#pragma unroll
    for (int off = 32; off; off >>= 1) v += __shfl_down(v, off);
    if (lane == 0) wred[n * 4 + wave] = v;
  }
  __syncthreads();

  float w[N_P];
#pragma unroll
  for (int n = 0; n < N_P; ++n)
    w[n] = wred[n * 4 + 0] + wred[n * 4 + 1] + wred[n * 4 + 2] + wred[n * 4 + 3];

  float4 g = {0.f, 0.f, 0.f, 0.f};
  float4 fm = {-INFINITY, -INFINITY, -INFINITY, -INFINITY};
#pragma unroll
  for (int n = 0; n < N_P; ++n) {
    const float4 f = fv[n];
    g.x += w[n] * f.x; g.y += w[n] * f.y; g.z += w[n] * f.z; g.w += w[n] * f.w;
    fm.x = fmaxf(fm.x, f.x); fm.y = fmaxf(fm.y, f.y);
    fm.z = fmaxf(fm.z, f.z); fm.w = fmaxf(fm.w, f.w);
  }
  ushort4 og, of;
  og.x = f2bf(g.x); og.y = f2bf(g.y); og.z = f2bf(g.z); og.w = f2bf(g.w);
  of.x = f2bf(fm.x); of.y = f2bf(fm.y); of.z = f2bf(fm.z); of.w = f2bf(fm.w);
  *(ushort4*)&Nbf[(size_t)t * D2_SZ + tid * 4] = og;
  *(ushort4*)&Nbf[(size_t)t * D2_SZ + D_SZ + tid * 4] = of;
}

// ---------------------------------------------------------------------------
// All 6 weight conversions in one launch. grid = (4096, 6).
// Wb row order: [tb | pb | ta | pa | gb | ga]
// ---------------------------------------------------------------------------
__global__ __launch_bounds__(256) void cvt_all(
    const float* __restrict__ Wtb, const float* __restrict__ Wpb,
    const float* __restrict__ Wta, const float* __restrict__ Wpa,
    const float* __restrict__ Wgb, const float* __restrict__ Wga,
    unsigned short* __restrict__ Wb) {
  const int r = blockIdx.y;
  const int i = blockIdx.x * 256 + threadIdx.x;
  const int n4 = (r < 4) ? (D_SZ * KDIM / 4) : (D2_SZ * KDIM / 4);
  if (i >= n4) return;
  const float* src;
  size_t off;
  switch (r) {
    case 0: src = Wtb; off = 0; break;
    case 1: src = Wpb; off = (size_t)1024 * KDIM; break;
    case 2: src = Wta; off = (size_t)2048 * KDIM; break;
    case 3: src = Wpa; off = (size_t)3072 * KDIM; break;
    case 4: src = Wgb; off = (size_t)4096 * KDIM; break;
    default: src = Wga; off = (size_t)6144 * KDIM; break;
  }
  const float4 v = ((const float4*)src)[i];
  ushort4 o;
  o.x = f2bf(v.x); o.y = f2bf(v.y); o.z = f2bf(v.z); o.w = f2bf(v.w);
  ((ushort4*)(Wb + off))[i] = o;
}

// ---------------------------------------------------------------------------
// Kernel B: fused projection GEMM, bf16 MFMA.
// [tb|pb|ta|pa] -> Cproj[token][4096] row-major.
// gb/ga        -> Gbt/Gat[f][token] TRANSPOSED (ushort4-packed per lane).
// 128x128 tile, 4 waves (2x2), 16x16x32 bf16 MFMA, BK=32, width-16 staging.
// ---------------------------------------------------------------------------
__global__ __launch_bounds__(256) void gemm_fused(
    const unsigned short* __restrict__ X,
    const unsigned short* __restrict__ Wb,
    unsigned short* __restrict__ Cproj,
    unsigned short* __restrict__ Gbt,
    unsigned short* __restrict__ Gat) {
  __shared__ __align__(16) unsigned short As[128 * 32];
  __shared__ __align__(16) unsigned short Bs[128 * 32];
  const int tid = threadIdx.x;
  const int lane = tid & 63;
  const int w = tid >> 6;
  const int m0 = blockIdx.x * 128;
  const int e0 = blockIdx.y * 128;
  const int wm = (w >> 1) * 64;
  const int wn = (w & 1) * 64;
  const int quad = lane >> 4;
  const int l15 = lane & 15;

  floatx4 acc[4][4];
#pragma unroll
  for (int mt = 0; mt < 4; ++mt)
#pragma unroll
    for (int nt = 0; nt < 4; ++nt) {
      floatx4 z = {0.f, 0.f, 0.f, 0.f};
      acc[mt][nt] = z;
    }

  const unsigned short* gA[2];
  const unsigned short* gB[2];
  unsigned short* lA[2];
  unsigned short* lB[2];
#pragma unroll
  for (int c = 0; c < 2; ++c) {
    const int chunk = w * 64 + lane + c * 256;
    const int row = chunk >> 2;
    const int cc = chunk & 3;
    gA[c] = X + (size_t)(m0 + row) * KDIM + cc * 8;
    gB[c] = Wb + (size_t)(e0 + row) * KDIM + cc * 8;
    lA[c] = &As[(size_t)(w * 64 + c * 256) * 8];  // wave-uniform base
    lB[c] = &Bs[(size_t)(w * 64 + c * 256) * 8];
  }

  for (int k0 = 0; k0 < KDIM; k0 += 32) {
#pragma unroll
    for (int c = 0; c < 2; ++c) {
      gload_lds16(gA[c] + k0, lA[c]);
      gload_lds16(gB[c] + k0, lB[c]);
    }
    __syncthreads();
    short8 a[4], b[4];
#pragma unroll
    for (int mt = 0; mt < 4; ++mt)
      a[mt] = *(const short8*)&As[(wm + mt * 16 + l15) * 32 + quad * 8];
#pragma unroll
    for (int nt = 0; nt < 4; ++nt)
      b[nt] = *(const short8*)&Bs[(wn + nt * 16 + l15) * 32 + quad * 8];
#pragma unroll
    for (int mt = 0; mt < 4; ++mt)
#pragma unroll
      for (int nt = 0; nt < 4; ++nt)
        acc[mt][nt] = __builtin_amdgcn_mfma_f32_16x16x32_bf16(
            a[mt], b[nt], acc[mt][nt], 0, 0, 0);
    __syncthreads();
  }

  if (blockIdx.y < 32) {
    // projection region: row-major [token][4096]
#pragma unroll
    for (int mt = 0; mt < 4; ++mt)
#pragma unroll
      for (int nt = 0; nt < 4; ++nt) {
        const int col = e0 + wn + nt * 16 + l15;
#pragma unroll
        for (int r = 0; r < 4; ++r) {
          const int rowg = m0 + wm + mt * 16 + quad * 4 + r;
          Cproj[(size_t)rowg * EPROJ + col] = f2bf(acc[mt][nt][r]);
        }
      }
  } else {
    // g region: transposed [f][token], 4 consecutive tokens -> ushort4
    unsigned short* Gt = (blockIdx.y < 48) ? Gbt : Gat;
    const int fb = e0 - ((blockIdx.y < 48) ? 4096 : 6144);
#pragma unroll
    for (int mt = 0; mt < 4; ++mt)
#pragma unroll
      for (int nt = 0; nt < 4; ++nt) {
        const int f = fb + wn + nt * 16 + l15;
        const int tok0 = m0 + wm + mt * 16 + quad * 4;
        ushort4 o;
        o.x = f2bf(acc[mt][nt][0]); o.y = f2bf(acc[mt][nt][1]);
        o.z = f2bf(acc[mt][nt][2]); o.w = f2bf(acc[mt][nt][3]);
        *(ushort4*)&Gt[(size_t)f * BT + tok0] = o;
      }
  }
}

// ---------------------------------------------------------------------------
// Kernel C: masked scores via MFMA, bf16 output.
// Sbf[br][b][i][j] = mask * scale * <A_i, B_j>, K=1024.
// ---------------------------------------------------------------------------
__global__ __launch_bounds__(256) void score_kernel(
    const unsigned short* __restrict__ Cproj, unsigned short* __restrict__ Sbf) {
  const int b = blockIdx.x;
  const int br = blockIdx.y;
  const int aoff = br ? 2048 : 0;   // ta : tb
  const int boff = aoff + 1024;     // pa : pb
  const float scale = 0.022097086912079608f;  // 1/sqrt(2*1024)

  __shared__ __align__(16) unsigned short As[128 * 32];
  __shared__ __align__(16) unsigned short Bs[128 * 32];
  const int tid = threadIdx.x;
  const int lane = tid & 63;
  const int w = tid >> 6;
  const int wm = (w >> 1) * 64;
  const int wn = (w & 1) * 64;
  const int quad = lane >> 4;
  const int l15 = lane & 15;
  const int t0 = b * T_SZ;

  floatx4 acc[4][4];
#pragma unroll
  for (int mt = 0; mt < 4; ++mt)
#pragma unroll
    for (int nt = 0; nt < 4; ++nt) {
      floatx4 z = {0.f, 0.f, 0.f, 0.f};
      acc[mt][nt] = z;
    }

  const unsigned short* gA[2];
  const unsigned short* gB[2];
  unsigned short* lA[2];
  unsigned short* lB[2];
#pragma unroll
  for (int c = 0; c < 2; ++c) {
    const int chunk = w * 64 + lane + c * 256;
    const int row = chunk >> 2;
    const int cc = chunk & 3;
    gA[c] = Cproj + (size_t)(t0 + row) * EPROJ + aoff + cc * 8;
    gB[c] = Cproj + (size_t)(t0 + row) * EPROJ + boff + cc * 8;
    lA[c] = &As[(size_t)(w * 64 + c * 256) * 8];
    lB[c] = &Bs[(size_t)(w * 64 + c * 256) * 8];
  }

  for (int k0 = 0; k0 < D_SZ; k0 += 32) {
#pragma unroll
    for (int c = 0; c < 2; ++c) {
      gload_lds16(gA[c] + k0, lA[c]);
      gload_lds16(gB[c] + k0, lB[c]);
    }
    __syncthreads();
    short8 a[4], bb[4];
#pragma unroll
    for (int mt = 0; mt < 4; ++mt)
      a[mt] = *(const short8*)&As[(wm + mt * 16 + l15) * 32 + quad * 8];
#pragma unroll
    for (int nt = 0; nt < 4; ++nt)
      bb[nt] = *(const short8*)&Bs[(wn + nt * 16 + l15) * 32 + quad * 8];
#pragma unroll
    for (int mt = 0; mt < 4; ++mt)
#pragma unroll
      for (int nt = 0; nt < 4; ++nt)
        acc[mt][nt] = __builtin_amdgcn_mfma_f32_16x16x32_bf16(
            a[mt], bb[nt], acc[mt][nt], 0, 0, 0);
    __syncthreads();
  }

  unsigned short* Sb = Sbf + ((size_t)br * B_SZ + b) * T_SZ * T_SZ;
#pragma unroll
  for (int mt = 0; mt < 4; ++mt)
#pragma unroll
    for (int nt = 0; nt < 4; ++nt) {
      const int j = wn + nt * 16 + l15;
#pragma unroll
      for (int r = 0; r < 4; ++r) {
        const int i = wm + mt * 16 + quad * 4 + r;
        const bool keep = br ? (j > i) : (j < i);
        Sb[(size_t)i * T_SZ + j] = f2bf(keep ? acc[mt][nt][r] * scale : 0.f);
      }
    }
}

// ---------------------------------------------------------------------------
// Kernel D: PV via MFMA, no LDS.
// out[t0+i][f0+f] = n + sum_j Sb[i][j]*Gbt[f][j] + sum_j Sa[i][j]*Gat[f][j]
// A-frag: 8 consecutive j from row-major S. B-frag: 8 consecutive tokens
// from Gt (transposed g). Grid (16 ftiles, 16 batches), K=128.
// ---------------------------------------------------------------------------
__global__ __launch_bounds__(256) void pv_mfma(
    const unsigned short* __restrict__ Nbf,
    const unsigned short* __restrict__ Sbf,
    const unsigned short* __restrict__ Gbt,
    const unsigned short* __restrict__ Gat,
    float* __restrict__ out) {
  const int ft = blockIdx.x;
  const int b = blockIdx.y;
  const int f0 = ft * 128;
  const int t0 = b * T_SZ;
  const int tid = threadIdx.x;
  const int lane = tid & 63;
  const int w = tid >> 6;
  const int wm = (w >> 1) * 64;   // token dim
  const int wn = (w & 1) * 64;    // f dim
  const int quad = lane >> 4;
  const int l15 = lane & 15;

  const unsigned short* Sb = Sbf + ((size_t)0 * B_SZ + b) * T_SZ * T_SZ;
  const unsigned short* Sa = Sbf + ((size_t)1 * B_SZ + b) * T_SZ * T_SZ;

  floatx4 acc[4][4];
#pragma unroll
  for (int mt = 0; mt < 4; ++mt)
#pragma unroll
    for (int nt = 0; nt < 4; ++nt) {
      floatx4 z = {0.f, 0.f, 0.f, 0.f};
      acc[mt][nt] = z;
    }

#pragma unroll
  for (int k0 = 0; k0 < T_SZ; k0 += 32) {
    short8 ab[4], aa[4], bb[4], ba[4];
#pragma unroll
    for (int mt = 0; mt < 4; ++mt) {
      const int i = wm + mt * 16 + l15;
      ab[mt] = *(const short8*)&Sb[(size_t)i * T_SZ + k0 + quad * 8];
      aa[mt] = *(const short8*)&Sa[(size_t)i * T_SZ + k0 + quad * 8];
    }
#pragma unroll
    for (int nt = 0; nt < 4; ++nt) {
      const int f = f0 + wn + nt * 16 + l15;
      bb[nt] = *(const short8*)&Gbt[(size_t)f * BT + t0 + k0 + quad * 8];
      ba[nt] = *(const short8*)&Gat[(size_t)f * BT + t0 + k0 + quad * 8];
    }
#pragma unroll
    for (int mt = 0; mt < 4; ++mt)
#pragma unroll
      for (int nt = 0; nt < 4; ++nt) {
        acc[mt][nt] = __builtin_amdgcn_mfma_f32_16x16x32_bf16(
            ab[mt], bb[nt], acc[mt][nt], 0, 0, 0);
        acc[mt][nt] = __builtin_amdgcn_mfma_f32_16x16x32_bf16(
            aa[mt], ba[nt], acc[mt][nt], 0, 0, 0);
      }
  }

#pragma unroll
  for (int mt = 0; mt < 4; ++mt)
#pragma unroll
    for (int nt = 0; nt < 4; ++nt) {
      const int f = f0 + wn + nt * 16 + l15;
#pragma unroll
      for (int r = 0; r < 4; ++r) {
        const int tok = t0 + wm + mt * 16 + quad * 4 + r;
        out[(size_t)tok * D2_SZ + f] =
            acc[mt][nt][r] + bf2f(Nbf[(size_t)tok * D2_SZ + f]);
      }
    }
}

// ---------------------------------------------------------------------------
extern "C" void kernel_launch(void* const* d_in, const int* in_sizes, int n_in,
                              void* d_out, int out_size, void* d_ws, size_t ws_size,
                              hipStream_t stream) {
  const float* feat = (const float*)d_in[0];
  const float* Wq  = (const float*)d_in[1];
  const float* Wtb = (const float*)d_in[2];
  const float* Wpb = (const float*)d_in[3];
  const float* Wgb = (const float*)d_in[4];  // dict order: gb before ta
  const float* Wta = (const float*)d_in[5];
  const float* Wpa = (const float*)d_in[6];
  const float* Wga = (const float*)d_in[7];
  float* out = (float*)d_out;

  unsigned short* ws = (unsigned short*)d_ws;
  unsigned short* Nbf   = ws;                                 // [2048][2048]
  unsigned short* Wb    = Nbf + (size_t)BT * D2_SZ;           // [8192][2048]
  unsigned short* Cproj = Wb + (size_t)EALL * KDIM;           // [2048][4096]
  unsigned short* Gbt   = Cproj + (size_t)BT * EPROJ;         // [2048][2048]
  unsigned short* Gat   = Gbt + (size_t)D2_SZ * BT;           // [2048][2048]
  unsigned short* Sbf   = Gat + (size_t)D2_SZ * BT;           // [2][16][128][128]

  build_n_kernel<<<BT, 256, 0, stream>>>(feat, Wq, Nbf);
  cvt_all<<<dim3(4096, 6), 256, 0, stream>>>(Wtb, Wpb, Wta, Wpa, Wgb, Wga, Wb);
  gemm_fused<<<dim3(BT / 128, EALL / 128), 256, 0, stream>>>(Nbf, Wb, Cproj, Gbt, Gat);
  score_kernel<<<dim3(B_SZ, 2), 256, 0, stream>>>(Cproj, Sbf);
  pv_mfma<<<dim3(D2_SZ / 128, B_SZ), 256, 0, stream>>>(Nbf, Sbf, Gbt, Gat, out);
}

// Round 5
// 332.622 us; speedup vs baseline: 6.5064x; 1.0303x over previous
//
#include <hip/hip_runtime.h>
#include <hip/hip_bf16.h>
#include <math.h>

#define B_SZ 16
#define T_SZ 128
#define N_P 12
#define D_SZ 1024
#define D2_SZ 2048
#define BT 2048          // B*T tokens
#define KDIM 2048        // inner dim of projections (2D)
#define EALL 8192        // 4*1024 (tb,pb,ta,pa) + 2*2048 (gb,ga)
#define EPROJ 4096       // tb|pb|ta|pa row width

typedef __attribute__((ext_vector_type(8))) short short8;    // 8 bf16 = 4 VGPRs
typedef __attribute__((ext_vector_type(4))) float floatx4;   // MFMA C/D

__device__ inline void gload_lds16(const void* g, void* l) {
  __builtin_amdgcn_global_load_lds(
      (const __attribute__((address_space(1))) void*)g,
      (__attribute__((address_space(3))) void*)l, 16, 0, 0);
}

__device__ inline unsigned short f2bf(float x) {
  union { __hip_bfloat16 h; unsigned short u; } cv;
  cv.h = __float2bfloat16(x);
  return cv.u;
}
__device__ inline float bf2f(unsigned short u) {
  return __uint_as_float(((unsigned)u) << 16);
}

// ---------------------------------------------------------------------------
// Kernel A: build n = [g ; max] per token, bf16 out. One block per token.
// ---------------------------------------------------------------------------
__global__ __launch_bounds__(256) void build_n_kernel(
    const float* __restrict__ feat, const float* __restrict__ Wq,
    unsigned short* __restrict__ Nbf) {
  const int t = blockIdx.x;
  const int tid = threadIdx.x;
  const float4* fb4 = (const float4*)(feat + (size_t)t * N_P * D_SZ);
  const float4* wq4 = (const float4*)Wq;

  float4 q = {0.f, 0.f, 0.f, 0.f};
#pragma unroll
  for (int m = 0; m < N_P; ++m) {
    const float4 v = wq4[m * 256 + tid];
    q.x += v.x; q.y += v.y; q.z += v.z; q.w += v.w;
  }

  float4 fv[N_P];
  float part[N_P];
#pragma unroll
  for (int n = 0; n < N_P; ++n) {
    const float4 f = fb4[n * 256 + tid];
    fv[n] = f;
    part[n] = f.x * q.x + f.y * q.y + f.z * q.z + f.w * q.w;
  }

  __shared__ float wred[N_P * 4];
  const int lane = tid & 63;
  const int wave = tid >> 6;
#pragma unroll
  for (int n = 0; n < N_P; ++n) {
    float v = part[n];
#pragma unroll
    for (int off = 32; off; off >>= 1) v += __shfl_down(v, off);
    if (lane == 0) wred[n * 4 + wave] = v;
  }
  __syncthreads();

  float w[N_P];
#pragma unroll
  for (int n = 0; n < N_P; ++n)
    w[n] = wred[n * 4 + 0] + wred[n * 4 + 1] + wred[n * 4 + 2] + wred[n * 4 + 3];

  float4 g = {0.f, 0.f, 0.f, 0.f};
  float4 fm = {-INFINITY, -INFINITY, -INFINITY, -INFINITY};
#pragma unroll
  for (int n = 0; n < N_P; ++n) {
    const float4 f = fv[n];
    g.x += w[n] * f.x; g.y += w[n] * f.y; g.z += w[n] * f.z; g.w += w[n] * f.w;
    fm.x = fmaxf(fm.x, f.x); fm.y = fmaxf(fm.y, f.y);
    fm.z = fmaxf(fm.z, f.z); fm.w = fmaxf(fm.w, f.w);
  }
  ushort4 og, of;
  og.x = f2bf(g.x); og.y = f2bf(g.y); og.z = f2bf(g.z); og.w = f2bf(g.w);
  of.x = f2bf(fm.x); of.y = f2bf(fm.y); of.z = f2bf(fm.z); of.w = f2bf(fm.w);
  *(ushort4*)&Nbf[(size_t)t * D2_SZ + tid * 4] = og;
  *(ushort4*)&Nbf[(size_t)t * D2_SZ + D_SZ + tid * 4] = of;
}

// ---------------------------------------------------------------------------
// Weight conversion. grid (2048, 6). r<4: 1 float4/thread; r>=4: 2 (g mats).
// Wb row order: [tb | pb | ta | pa | gb | ga]
// ---------------------------------------------------------------------------
__global__ __launch_bounds__(256) void cvt_all(
    const float* __restrict__ Wtb, const float* __restrict__ Wpb,
    const float* __restrict__ Wta, const float* __restrict__ Wpa,
    const float* __restrict__ Wgb, const float* __restrict__ Wga,
    unsigned short* __restrict__ Wb) {
  const int r = blockIdx.y;
  const int i = blockIdx.x * 256 + threadIdx.x;   // < 524288
  const float* src;
  size_t off;
  switch (r) {
    case 0: src = Wtb; off = 0; break;
    case 1: src = Wpb; off = (size_t)1024 * KDIM; break;
    case 2: src = Wta; off = (size_t)2048 * KDIM; break;
    case 3: src = Wpa; off = (size_t)3072 * KDIM; break;
    case 4: src = Wgb; off = (size_t)4096 * KDIM; break;
    default: src = Wga; off = (size_t)6144 * KDIM; break;
  }
  {
    const float4 v = ((const float4*)src)[i];
    ushort4 o;
    o.x = f2bf(v.x); o.y = f2bf(v.y); o.z = f2bf(v.z); o.w = f2bf(v.w);
    ((ushort4*)(Wb + off))[i] = o;
  }
  if (r >= 4) {
    const int i2 = i + 524288;
    const float4 v = ((const float4*)src)[i2];
    ushort4 o;
    o.x = f2bf(v.x); o.y = f2bf(v.y); o.z = f2bf(v.z); o.w = f2bf(v.w);
    ((ushort4*)(Wb + off))[i2] = o;
  }
}

// ---------------------------------------------------------------------------
// Kernel B: fused projection GEMM, bf16 MFMA.
// XOR bank swizzle: LDS slot s holds global chunk col (s&3) ^ ((row>>1)&3).
// 128x128 tile, 4 waves (2x2), 16x16x32 bf16 MFMA, BK=32, width-16 staging.
// ---------------------------------------------------------------------------
__global__ __launch_bounds__(256) void gemm_fused(
    const unsigned short* __restrict__ X,
    const unsigned short* __restrict__ Wb,
    unsigned short* __restrict__ Cproj,
    unsigned short* __restrict__ Gbt,
    unsigned short* __restrict__ Gat) {
  __shared__ __align__(16) unsigned short As[128 * 32];
  __shared__ __align__(16) unsigned short Bs[128 * 32];
  const int tid = threadIdx.x;
  const int lane = tid & 63;
  const int w = tid >> 6;
  const int m0 = blockIdx.x * 128;
  const int e0 = blockIdx.y * 128;
  const int wm = (w >> 1) * 64;
  const int wn = (w & 1) * 64;
  const int quad = lane >> 4;
  const int l15 = lane & 15;

  floatx4 acc[4][4];
#pragma unroll
  for (int mt = 0; mt < 4; ++mt)
#pragma unroll
    for (int nt = 0; nt < 4; ++nt) {
      floatx4 z = {0.f, 0.f, 0.f, 0.f};
      acc[mt][nt] = z;
    }

  const unsigned short* gA[2];
  const unsigned short* gB[2];
  unsigned short* lA[2];
  unsigned short* lB[2];
#pragma unroll
  for (int c = 0; c < 2; ++c) {
    const int s = w * 64 + lane + c * 256;
    const int row = s >> 2;
    const int ccg = (s & 3) ^ ((row >> 1) & 3);   // swizzled source chunk
    gA[c] = X + (size_t)(m0 + row) * KDIM + ccg * 8;
    gB[c] = Wb + (size_t)(e0 + row) * KDIM + ccg * 8;
    lA[c] = &As[(size_t)s * 8];   // wave-uniform base + lane*16B
    lB[c] = &Bs[(size_t)s * 8];
  }

  // loop-invariant swizzled fragment offsets
  int aofs[4], bofs[4];
#pragma unroll
  for (int mt = 0; mt < 4; ++mt) {
    const int row = wm + mt * 16 + l15;
    aofs[mt] = row * 32 + ((quad ^ ((row >> 1) & 3)) * 8);
  }
#pragma unroll
  for (int nt = 0; nt < 4; ++nt) {
    const int row = wn + nt * 16 + l15;
    bofs[nt] = row * 32 + ((quad ^ ((row >> 1) & 3)) * 8);
  }

  for (int k0 = 0; k0 < KDIM; k0 += 32) {
#pragma unroll
    for (int c = 0; c < 2; ++c) {
      gload_lds16(gA[c] + k0, lA[c]);
      gload_lds16(gB[c] + k0, lB[c]);
    }
    __syncthreads();
    short8 a[4], b[4];
#pragma unroll
    for (int mt = 0; mt < 4; ++mt) a[mt] = *(const short8*)&As[aofs[mt]];
#pragma unroll
    for (int nt = 0; nt < 4; ++nt) b[nt] = *(const short8*)&Bs[bofs[nt]];
#pragma unroll
    for (int mt = 0; mt < 4; ++mt)
#pragma unroll
      for (int nt = 0; nt < 4; ++nt)
        acc[mt][nt] = __builtin_amdgcn_mfma_f32_16x16x32_bf16(
            a[mt], b[nt], acc[mt][nt], 0, 0, 0);
    __syncthreads();
  }

  if (blockIdx.y < 32) {
#pragma unroll
    for (int mt = 0; mt < 4; ++mt)
#pragma unroll
      for (int nt = 0; nt < 4; ++nt) {
        const int col = e0 + wn + nt * 16 + l15;
#pragma unroll
        for (int r = 0; r < 4; ++r) {
          const int rowg = m0 + wm + mt * 16 + quad * 4 + r;
          Cproj[(size_t)rowg * EPROJ + col] = f2bf(acc[mt][nt][r]);
        }
      }
  } else {
    unsigned short* Gt = (blockIdx.y < 48) ? Gbt : Gat;
    const int fb = e0 - ((blockIdx.y < 48) ? 4096 : 6144);
#pragma unroll
    for (int mt = 0; mt < 4; ++mt)
#pragma unroll
      for (int nt = 0; nt < 4; ++nt) {
        const int f = fb + wn + nt * 16 + l15;
        const int tok0 = m0 + wm + mt * 16 + quad * 4;
        ushort4 o;
        o.x = f2bf(acc[mt][nt][0]); o.y = f2bf(acc[mt][nt][1]);
        o.z = f2bf(acc[mt][nt][2]); o.w = f2bf(acc[mt][nt][3]);
        *(ushort4*)&Gt[(size_t)f * BT + tok0] = o;
      }
  }
}

// ---------------------------------------------------------------------------
// Kernel C: score partials via MFMA. grid (16 batches, 2 branches, 4 K-chunks).
// Spart[(br*16+b)*4+kc][i][j] (fp32, unmasked, unscaled).
// ---------------------------------------------------------------------------
__global__ __launch_bounds__(256) void score_kernel(
    const unsigned short* __restrict__ Cproj, float* __restrict__ Spart) {
  const int b = blockIdx.x;
  const int br = blockIdx.y;
  const int kc = blockIdx.z;
  const int aoff = br ? 2048 : 0;   // ta : tb
  const int boff = aoff + 1024;     // pa : pb

  __shared__ __align__(16) unsigned short As[128 * 32];
  __shared__ __align__(16) unsigned short Bs[128 * 32];
  const int tid = threadIdx.x;
  const int lane = tid & 63;
  const int w = tid >> 6;
  const int wm = (w >> 1) * 64;
  const int wn = (w & 1) * 64;
  const int quad = lane >> 4;
  const int l15 = lane & 15;
  const int t0 = b * T_SZ;

  floatx4 acc[4][4];
#pragma unroll
  for (int mt = 0; mt < 4; ++mt)
#pragma unroll
    for (int nt = 0; nt < 4; ++nt) {
      floatx4 z = {0.f, 0.f, 0.f, 0.f};
      acc[mt][nt] = z;
    }

  const unsigned short* gA[2];
  const unsigned short* gB[2];
  unsigned short* lA[2];
  unsigned short* lB[2];
#pragma unroll
  for (int c = 0; c < 2; ++c) {
    const int s = w * 64 + lane + c * 256;
    const int row = s >> 2;
    const int ccg = (s & 3) ^ ((row >> 1) & 3);
    gA[c] = Cproj + (size_t)(t0 + row) * EPROJ + aoff + ccg * 8;
    gB[c] = Cproj + (size_t)(t0 + row) * EPROJ + boff + ccg * 8;
    lA[c] = &As[(size_t)s * 8];
    lB[c] = &Bs[(size_t)s * 8];
  }

  int aofs[4], bofs[4];
#pragma unroll
  for (int mt = 0; mt < 4; ++mt) {
    const int row = wm + mt * 16 + l15;
    aofs[mt] = row * 32 + ((quad ^ ((row >> 1) & 3)) * 8);
  }
#pragma unroll
  for (int nt = 0; nt < 4; ++nt) {
    const int row = wn + nt * 16 + l15;
    bofs[nt] = row * 32 + ((quad ^ ((row >> 1) & 3)) * 8);
  }

  const int kbeg = kc * 256;
  for (int k0 = kbeg; k0 < kbeg + 256; k0 += 32) {
#pragma unroll
    for (int c = 0; c < 2; ++c) {
      gload_lds16(gA[c] + k0, lA[c]);
      gload_lds16(gB[c] + k0, lB[c]);
    }
    __syncthreads();
    short8 a[4], bb[4];
#pragma unroll
    for (int mt = 0; mt < 4; ++mt) a[mt] = *(const short8*)&As[aofs[mt]];
#pragma unroll
    for (int nt = 0; nt < 4; ++nt) bb[nt] = *(const short8*)&Bs[bofs[nt]];
#pragma unroll
    for (int mt = 0; mt < 4; ++mt)
#pragma unroll
      for (int nt = 0; nt < 4; ++nt)
        acc[mt][nt] = __builtin_amdgcn_mfma_f32_16x16x32_bf16(
            a[mt], bb[nt], acc[mt][nt], 0, 0, 0);
    __syncthreads();
  }

  float* Sp = Spart + ((size_t)(br * B_SZ + b) * 4 + kc) * T_SZ * T_SZ;
#pragma unroll
  for (int mt = 0; mt < 4; ++mt)
#pragma unroll
    for (int nt = 0; nt < 4; ++nt) {
      const int j = wn + nt * 16 + l15;
#pragma unroll
      for (int r = 0; r < 4; ++r) {
        const int i = wm + mt * 16 + quad * 4 + r;
        Sp[(size_t)i * T_SZ + j] = acc[mt][nt][r];
      }
    }
}

// ---------------------------------------------------------------------------
// Combine: Sbf = f2bf(mask * scale * sum_kc Spart). 512 blocks x 256 thr,
// one j4-group (4 cols) per thread.
// ---------------------------------------------------------------------------
__global__ __launch_bounds__(256) void score_combine(
    const float* __restrict__ Spart, unsigned short* __restrict__ Sbf) {
  const float scale = 0.022097086912079608f;  // 1/sqrt(2*1024)
  const int gid = blockIdx.x * 256 + threadIdx.x;   // < 131072
  const int j4 = gid & 31;
  const int i = (gid >> 5) & 127;
  const int bb = (gid >> 12) & 15;
  const int br = gid >> 16;
  const size_t base = ((size_t)(br * B_SZ + bb) * 4) * T_SZ * T_SZ +
                      (size_t)i * T_SZ + j4 * 4;
  float4 s = {0.f, 0.f, 0.f, 0.f};
#pragma unroll
  for (int kc = 0; kc < 4; ++kc) {
    const float4 v = *(const float4*)&Spart[base + (size_t)kc * T_SZ * T_SZ];
    s.x += v.x; s.y += v.y; s.z += v.z; s.w += v.w;
  }
  const int j0 = j4 * 4;
  ushort4 o;
  o.x = f2bf((br ? (j0 + 0 > i) : (j0 + 0 < i)) ? s.x * scale : 0.f);
  o.y = f2bf((br ? (j0 + 1 > i) : (j0 + 1 < i)) ? s.y * scale : 0.f);
  o.z = f2bf((br ? (j0 + 2 > i) : (j0 + 2 < i)) ? s.z * scale : 0.f);
  o.w = f2bf((br ? (j0 + 3 > i) : (j0 + 3 < i)) ? s.w * scale : 0.f);
  *(ushort4*)&Sbf[((size_t)(br * B_SZ + bb)) * T_SZ * T_SZ +
                  (size_t)i * T_SZ + j0] = o;
}

// ---------------------------------------------------------------------------
// Kernel D: PV via MFMA, no LDS.
// ---------------------------------------------------------------------------
__global__ __launch_bounds__(256) void pv_mfma(
    const unsigned short* __restrict__ Nbf,
    const unsigned short* __restrict__ Sbf,
    const unsigned short* __restrict__ Gbt,
    const unsigned short* __restrict__ Gat,
    float* __restrict__ out) {
  const int ft = blockIdx.x;
  const int b = blockIdx.y;
  const int f0 = ft * 128;
  const int t0 = b * T_SZ;
  const int tid = threadIdx.x;
  const int lane = tid & 63;
  const int w = tid >> 6;
  const int wm = (w >> 1) * 64;   // token dim
  const int wn = (w & 1) * 64;    // f dim
  const int quad = lane >> 4;
  const int l15 = lane & 15;

  const unsigned short* Sb = Sbf + ((size_t)0 * B_SZ + b) * T_SZ * T_SZ;
  const unsigned short* Sa = Sbf + ((size_t)1 * B_SZ + b) * T_SZ * T_SZ;

  floatx4 acc[4][4];
#pragma unroll
  for (int mt = 0; mt < 4; ++mt)
#pragma unroll
    for (int nt = 0; nt < 4; ++nt) {
      floatx4 z = {0.f, 0.f, 0.f, 0.f};
      acc[mt][nt] = z;
    }

#pragma unroll
  for (int k0 = 0; k0 < T_SZ; k0 += 32) {
    short8 ab[4], aa[4], bb[4], ba[4];
#pragma unroll
    for (int mt = 0; mt < 4; ++mt) {
      const int i = wm + mt * 16 + l15;
      ab[mt] = *(const short8*)&Sb[(size_t)i * T_SZ + k0 + quad * 8];
      aa[mt] = *(const short8*)&Sa[(size_t)i * T_SZ + k0 + quad * 8];
    }
#pragma unroll
    for (int nt = 0; nt < 4; ++nt) {
      const int f = f0 + wn + nt * 16 + l15;
      bb[nt] = *(const short8*)&Gbt[(size_t)f * BT + t0 + k0 + quad * 8];
      ba[nt] = *(const short8*)&Gat[(size_t)f * BT + t0 + k0 + quad * 8];
    }
#pragma unroll
    for (int mt = 0; mt < 4; ++mt)
#pragma unroll
      for (int nt = 0; nt < 4; ++nt) {
        acc[mt][nt] = __builtin_amdgcn_mfma_f32_16x16x32_bf16(
            ab[mt], bb[nt], acc[mt][nt], 0, 0, 0);
        acc[mt][nt] = __builtin_amdgcn_mfma_f32_16x16x32_bf16(
            aa[mt], ba[nt], acc[mt][nt], 0, 0, 0);
      }
  }

#pragma unroll
  for (int mt = 0; mt < 4; ++mt)
#pragma unroll
    for (int nt = 0; nt < 4; ++nt) {
      const int f = f0 + wn + nt * 16 + l15;
#pragma unroll
      for (int r = 0; r < 4; ++r) {
        const int tok = t0 + wm + mt * 16 + quad * 4 + r;
        out[(size_t)tok * D2_SZ + f] =
            acc[mt][nt][r] + bf2f(Nbf[(size_t)tok * D2_SZ + f]);
      }
    }
}

// ---------------------------------------------------------------------------
extern "C" void kernel_launch(void* const* d_in, const int* in_sizes, int n_in,
                              void* d_out, int out_size, void* d_ws, size_t ws_size,
                              hipStream_t stream) {
  const float* feat = (const float*)d_in[0];
  const float* Wq  = (const float*)d_in[1];
  const float* Wtb = (const float*)d_in[2];
  const float* Wpb = (const float*)d_in[3];
  const float* Wgb = (const float*)d_in[4];  // dict order: gb before ta
  const float* Wta = (const float*)d_in[5];
  const float* Wpa = (const float*)d_in[6];
  const float* Wga = (const float*)d_in[7];
  float* out = (float*)d_out;

  unsigned short* ws = (unsigned short*)d_ws;
  unsigned short* Nbf   = ws;                                 // [2048][2048] bf16
  unsigned short* Wb    = Nbf + (size_t)BT * D2_SZ;           // [8192][2048] bf16
  unsigned short* Cproj = Wb + (size_t)EALL * KDIM;           // [2048][4096] bf16
  unsigned short* Gbt   = Cproj + (size_t)BT * EPROJ;         // [2048][2048] bf16
  unsigned short* Gat   = Gbt + (size_t)D2_SZ * BT;           // [2048][2048] bf16
  unsigned short* Sbf   = Gat + (size_t)D2_SZ * BT;           // [2][16][128][128] bf16
  float* Spart = (float*)(Sbf + (size_t)2 * B_SZ * T_SZ * T_SZ); // [2][16][4][128][128] f32

  build_n_kernel<<<BT, 256, 0, stream>>>(feat, Wq, Nbf);
  cvt_all<<<dim3(2048, 6), 256, 0, stream>>>(Wtb, Wpb, Wta, Wpa, Wgb, Wga, Wb);
  gemm_fused<<<dim3(BT / 128, EALL / 128), 256, 0, stream>>>(Nbf, Wb, Cproj, Gbt, Gat);
  score_kernel<<<dim3(B_SZ, 2, 4), 256, 0, stream>>>(Cproj, Spart);
  score_combine<<<512, 256, 0, stream>>>(Spart, Sbf);
  pv_mfma<<<dim3(D2_SZ / 128, B_SZ), 256, 0, stream>>>(Nbf, Sbf, Gbt, Gat, out);
}